// Round 6
// baseline (483.143 us; speedup 1.0000x reference)
//
#include <hip/hip_runtime.h>

typedef __bf16 bf16_t;
typedef __bf16 bf16x2 __attribute__((ext_vector_type(2)));
typedef __bf16 bf16x8 __attribute__((ext_vector_type(8)));
typedef float f32x4 __attribute__((ext_vector_type(4)));

#define BN_EPS 1e-3f

// ---------------- fp32 -> bf16 elementwise convert (8 elems/thread) ----------------
__global__ __launch_bounds__(256) void cvt_f32_bf16(
    const float* __restrict__ in, bf16_t* __restrict__ out, long n)
{
  long i = ((long)blockIdx.x * 256 + threadIdx.x) * 8;
  if (i + 8 > n) return;
  f32x4 a = *(const f32x4*)(in + i);
  f32x4 b = *(const f32x4*)(in + i + 4);
  bf16x8 o;
  o[0] = (bf16_t)a[0]; o[1] = (bf16_t)a[1]; o[2] = (bf16_t)a[2]; o[3] = (bf16_t)a[3];
  o[4] = (bf16_t)b[0]; o[5] = (bf16_t)b[1]; o[6] = (bf16_t)b[2]; o[7] = (bf16_t)b[3];
  *(bf16x8*)(out + i) = o;
}

// ---------------- weight transpose fp32 in[R][C] -> bf16 out[C][R] ----------------
__global__ __launch_bounds__(256) void transpose_f32_bf16(
    const float* __restrict__ in, bf16_t* __restrict__ out, int R, int C)
{
  __shared__ bf16_t t[32][33];
  int bx = blockIdx.x * 32, by = blockIdx.y * 32;
  int tx = threadIdx.x, ty = threadIdx.y;
#pragma unroll
  for (int i = 0; i < 32; i += 8)
    t[ty + i][tx] = (bf16_t)in[(long)(by + ty + i) * C + (bx + tx)];
  __syncthreads();
#pragma unroll
  for (int i = 0; i < 32; i += 8)
    out[(long)(bx + ty + i) * R + (by + tx)] = t[tx][ty + i];
}

// ------- Wkv split-transpose: fp32 [256][640] -> WkT[128][256], WvT[512][256] bf16 -------
__global__ __launch_bounds__(256) void wkv_split_transpose(
    const float* __restrict__ in, bf16_t* __restrict__ outK, bf16_t* __restrict__ outV)
{
  __shared__ bf16_t t[32][33];
  int bx = blockIdx.x * 32, by = blockIdx.y * 32;   // bx over 640 cols, by over 256 rows
  int tx = threadIdx.x, ty = threadIdx.y;
#pragma unroll
  for (int i = 0; i < 32; i += 8)
    t[ty + i][tx] = (bf16_t)in[(long)(by + ty + i) * 640 + (bx + tx)];
  __syncthreads();
#pragma unroll
  for (int i = 0; i < 32; i += 8) {
    int c = bx + ty + i;                 // kv channel 0..639
    int h = c / 80, r80 = c - h * 80;
    bf16_t v = t[tx][ty + i];
    if (r80 < 16)
      outK[(long)(h * 16 + r80) * 256 + (by + tx)] = v;
    else
      outV[(long)(h * 64 + (r80 - 16)) * 256 + (by + tx)] = v;
  }
}

// ---------------- fused GEMM + BN (+ scatter epilogues) ----------------
// MODE 0: K   A=xb[32768][256], WkT[128][256] -> K[bh][4096][16]
// MODE 1: Q   A=xb (strided row gather), WqT[128][256] -> Q[bh][1024][32] (pad 0, *0.25*log2e)
// MODE 2: PROJ A=outp[8192][512], WpT[512][512] -> d_out fp32 [8192][512]
// MODE 3: V^T A=WvT[512][256], B=xb -> Vt[bh*64+dv][4096]  (coalesced Vt writes)
template <int MODE>
__global__ __launch_bounds__(256) void gemm_bn(
    const bf16_t* __restrict__ A, const bf16_t* __restrict__ Wt,
    const float* __restrict__ bias, const float* __restrict__ gamma,
    const float* __restrict__ beta, const float* __restrict__ mean,
    const float* __restrict__ var,
    bf16_t* __restrict__ out0, float* __restrict__ outf)
{
  constexpr int KTOT = (MODE == 2) ? 512 : 256;
  const int lane = threadIdx.x & 63;
  const int w = threadIdx.x >> 6;
  const int quad = lane >> 4, l15 = lane & 15;
  const int m0 = blockIdx.x * 64 + w * 16;
  const int n0 = blockIdx.y * 64;

  int mrow = m0 + l15;
  int arow;
  if constexpr (MODE == 1) {
    int b = mrow >> 10, qp = mrow & 1023;
    arow = (b << 12) + ((qp >> 5) << 7) + ((qp & 31) << 1);
  } else {
    arow = mrow;
  }
  const bf16_t* ap = A + (long)arow * KTOT + quad * 8;
  const bf16_t* bp = Wt + (long)(n0 + l15) * KTOT + quad * 8;

  f32x4 acc[4] = {};
#pragma unroll
  for (int ks = 0; ks < KTOT / 32; ks++) {
    bf16x8 a = *(const bf16x8*)(ap + ks * 32);
#pragma unroll
    for (int nt = 0; nt < 4; nt++) {
      bf16x8 bfr = *(const bf16x8*)(bp + (long)nt * 16 * KTOT + ks * 32);
      acc[nt] = __builtin_amdgcn_mfma_f32_16x16x32_bf16(a, bfr, acc[nt], 0, 0, 0);
    }
  }

  if constexpr (MODE == 3) {
    // rows = V channels, cols = x rows. BN per ROW.
    float sB[4], tB[4], bB[4];
#pragma unroll
    for (int r = 0; r < 4; r++) {
      int ch = m0 + quad * 4 + r;                      // 0..511
      int c = (ch >> 6) * 80 + 16 + (ch & 63);         // kv param index
      sB[r] = gamma[c] / sqrtf(var[c] + BN_EPS);
      tB[r] = beta[c] - mean[c] * sB[r];
      bB[r] = bias[c];
    }
#pragma unroll
    for (int nt = 0; nt < 4; nt++) {
      int n = n0 + nt * 16 + l15;                      // x row
      int b = n >> 12, seq = n & 4095;
#pragma unroll
      for (int r = 0; r < 4; r++) {
        int ch = m0 + quad * 4 + r;
        float y = (acc[nt][r] + bB[r]) * sB[r] + tB[r];
        out0[((long)((b * 8 + (ch >> 6)) * 64 + (ch & 63))) * 4096 + seq] = (bf16_t)y;
      }
    }
    return;
  }

#pragma unroll
  for (int nt = 0; nt < 4; nt++) {
    int col = n0 + nt * 16 + l15;
    int cp;
    if constexpr (MODE == 0) cp = (col >> 4) * 80 + (col & 15);
    else cp = col;
    float s = gamma[cp] / sqrtf(var[cp] + BN_EPS);
    float t = beta[cp] - mean[cp] * s;
    float bia = bias[cp];
#pragma unroll
    for (int r = 0; r < 4; r++) {
      int grow = m0 + quad * 4 + r;
      float y = (acc[nt][r] + bia) * s + t;
      if constexpr (MODE == 0) {
        int h = col >> 4, d = col & 15;
        int b = grow >> 12, seq = grow & 4095;
        out0[((long)((b * 8 + h) * 4096 + seq)) * 16 + d] = (bf16_t)y;   // K [bh][seq][16]
      } else if constexpr (MODE == 1) {
        int h = col >> 4, d = col & 15;
        int b = grow >> 10, qp = grow & 1023;
        long qi = ((long)((b * 8 + h) * 1024 + qp)) * 32 + d;
        out0[qi] = (bf16_t)(y * 0.36067376f);  // 0.25 (kd^-.5) * log2(e), for exp2 softmax
        out0[qi + 16] = (bf16_t)0.f;           // zero-pad d 16..31 (K-overread harmless)
      } else {
        outf[(long)grow * 512 + col] = y;
      }
    }
  }
}

// ---------------- flash attention: 8 waves = 2 qg x 4-way key split ----------------
// grid 1024: bh = blockIdx&63 (XCD locality), qb = blockIdx>>6 (16 q-blocks of 64).
// wave w: qg=w&1 (32 q rows), kq=w>>1 (keys kq*1024..+1024, 32 tiles of 32).
// Interleaved keys: kf0 = even (2*l15), kf1 = odd -> P writes pack to b32, P stays
// natural key order so V loads / P reads unchanged. exp2 softmax (scale in Q).
__global__ __launch_bounds__(512, 4) void attn_kernel(
    const bf16_t* __restrict__ Q, const bf16_t* __restrict__ K,
    const bf16_t* __restrict__ Vt, bf16_t* __restrict__ outp)
{
  const int tid = threadIdx.x;
  const int lane = tid & 63, w = tid >> 6;
  const int quad = lane >> 4, l15 = lane & 15;
  const int qg = w & 1, kq = w >> 1;
  const int bh = blockIdx.x & 63, qb = blockIdx.x >> 6;
  const int b = bh >> 3, h = bh & 7;
  const bf16_t* Qp = Q + (long)bh * 1024 * 32;
  const bf16_t* Kp = K + (long)bh * 4096 * 16;
  const bf16_t* Vp = Vt + (long)bh * 64 * 4096;

  // P: 8 waves x 2 strips x [16 rows x stride 40] bf16 = 20480 B (head of smem)
  // combine: 2 qg x 3 partials x 64 lanes x 40 f32 = 61440 B (aliased after loop)
  __shared__ __align__(16) char smem[61440];
  bf16_t* Pw0 = (bf16_t*)smem + (w * 2 + 0) * 640;
  bf16_t* Pw1 = (bf16_t*)smem + (w * 2 + 1) * 640;

  const int q0 = qb * 64 + qg * 32;
  bf16x8 qf[2];
  qf[0] = *(const bf16x8*)(Qp + (long)(q0 + l15) * 32 + quad * 8);
  qf[1] = *(const bf16x8*)(Qp + (long)(q0 + 16 + l15) * 32 + quad * 8);

  f32x4 O[2][4] = {};
  float lp[2][4] = {};
  const f32x4 zf = {0.f, 0.f, 0.f, 0.f};

  const int kstart = kq * 1024;
  // kf0: key rows 2*l15 (even); kf1: 2*l15+1 (odd). Quads 2,3 overread into the
  // next row -> multiplied by Q's zero-pad -> exact 0.
  const bf16_t* kpb = Kp + (long)(kstart + 2 * l15) * 16 + quad * 8;
  const bf16_t* vpb = Vp + (long)l15 * 4096 + kstart + quad * 8;

  auto loadK = [&](int t, bf16x8& k0, bf16x8& k1) {
    k0 = *(const bf16x8*)(kpb + (long)t * 512);
    k1 = *(const bf16x8*)(kpb + (long)t * 512 + 16);
  };
  auto loadV = [&](int t, bf16x8* v) {
#pragma unroll
    for (int dt = 0; dt < 4; dt++)
      v[dt] = *(const bf16x8*)(vpb + (long)dt * 65536 + t * 32);
  };
  auto qk_part = [&](bf16x8 kf0, bf16x8 kf1) {
#pragma unroll
    for (int s = 0; s < 2; s++) {
      f32x4 S0 = __builtin_amdgcn_mfma_f32_16x16x32_bf16(qf[s], kf0, zf, 0, 0, 0);
      f32x4 S1 = __builtin_amdgcn_mfma_f32_16x16x32_bf16(qf[s], kf1, zf, 0, 0, 0);
      bf16_t* P = s ? Pw1 : Pw0;
#pragma unroll
      for (int r = 0; r < 4; r++) {
        float p0 = exp2f(S0[r]);       // key 2*l15 (+tile)
        float p1 = exp2f(S1[r]);       // key 2*l15+1
        lp[s][r] += p0 + p1;
        bf16x2 pk; pk[0] = (bf16_t)p0; pk[1] = (bf16_t)p1;
        *(bf16x2*)(P + (quad * 4 + r) * 40 + 2 * l15) = pk;   // packed b32 write
      }
    }
  };
  auto pv_part = [&](const bf16x8* vf) {
    __asm__ volatile("s_waitcnt lgkmcnt(0)" ::: "memory");
#pragma unroll
    for (int s = 0; s < 2; s++) {
      bf16x8 pf = *(const bf16x8*)((s ? Pw1 : Pw0) + l15 * 40 + quad * 8);
#pragma unroll
      for (int dt = 0; dt < 4; dt++)
        O[s][dt] = __builtin_amdgcn_mfma_f32_16x16x32_bf16(pf, vf[dt], O[s][dt], 0, 0, 0);
    }
  };

  // 2-deep pipeline over 32 tiles; tail loads (t=32,33) overread into the
  // adjacent workspace buffers (in-bounds, unused).
  bf16x8 ak0, ak1, bk0, bk1, av[4], bv[4];
  loadK(0, ak0, ak1); loadV(0, av);
  loadK(1, bk0, bk1); loadV(1, bv);
  for (int kt = 0; kt < 32; kt += 2) {
    qk_part(ak0, ak1);
    loadK(kt + 2, ak0, ak1);
    pv_part(av);
    loadV(kt + 2, av);
    qk_part(bk0, bk1);
    loadK(kt + 3, bk0, bk1);
    pv_part(bv);
    loadV(kt + 3, bv);
  }

  // ------- combine 4 key-quarters -------
  __syncthreads();
  float* comb = (float*)smem;
  if (kq != 0) {
    float* dst = comb + ((long)(qg * 3 + (kq - 1)) * 64 + lane) * 40;
#pragma unroll
    for (int s = 0; s < 2; s++)
#pragma unroll
      for (int dt = 0; dt < 4; dt++)
        *(f32x4*)(dst + (s * 4 + dt) * 4) = O[s][dt];
#pragma unroll
    for (int s = 0; s < 2; s++)
#pragma unroll
      for (int r = 0; r < 4; r++)
        dst[32 + s * 4 + r] = lp[s][r];
  }
  __syncthreads();
  if (kq == 0) {
#pragma unroll
    for (int j = 0; j < 3; j++) {
      const float* src = comb + ((long)(qg * 3 + j) * 64 + lane) * 40;
#pragma unroll
      for (int s = 0; s < 2; s++)
#pragma unroll
        for (int dt = 0; dt < 4; dt++)
          O[s][dt] += *(const f32x4*)(src + (s * 4 + dt) * 4);
#pragma unroll
      for (int s = 0; s < 2; s++)
#pragma unroll
        for (int r = 0; r < 4; r++)
          lp[s][r] += src[32 + s * 4 + r];
    }

#pragma unroll
    for (int s = 0; s < 2; s++) {
      float lt[4];
#pragma unroll
      for (int r = 0; r < 4; r++) {
        float v = lp[s][r];
        v += __shfl_xor(v, 1);
        v += __shfl_xor(v, 2);
        v += __shfl_xor(v, 4);
        v += __shfl_xor(v, 8);
        lt[r] = v;
      }
#pragma unroll
      for (int dt = 0; dt < 4; dt++) {
        int dv = dt * 16 + l15;
#pragma unroll
        for (int r = 0; r < 4; r++) {
          int q = q0 + s * 16 + quad * 4 + r;
          float val = O[s][dt][r] / lt[r];
          float hs = val * fminf(fmaxf(val + 3.f, 0.f), 6.f) * (1.f / 6.f);
          long row = (long)h * 128 + dv * 2 + (q >> 9);
          outp[((long)b * 1024 + row) * 512 + (q & 511)] = (bf16_t)hs;
        }
      }
    }
  }
}

extern "C" void kernel_launch(void* const* d_in, const int* in_sizes, int n_in,
                              void* d_out, int out_size, void* d_ws, size_t ws_size,
                              hipStream_t stream)
{
  const float* x    = (const float*)d_in[0];
  const float* Wkv  = (const float*)d_in[1];
  const float* bkv  = (const float*)d_in[2];
  const float* g_kv = (const float*)d_in[3];
  const float* b_kv = (const float*)d_in[4];
  const float* m_kv = (const float*)d_in[5];
  const float* v_kv = (const float*)d_in[6];
  const float* Wq   = (const float*)d_in[7];
  const float* bq   = (const float*)d_in[8];
  const float* g_q  = (const float*)d_in[9];
  const float* b_q  = (const float*)d_in[10];
  const float* m_q  = (const float*)d_in[11];
  const float* v_q  = (const float*)d_in[12];
  const float* Wp   = (const float*)d_in[13];
  const float* bp   = (const float*)d_in[14];
  const float* g_p  = (const float*)d_in[15];
  const float* b_p  = (const float*)d_in[16];
  const float* m_p  = (const float*)d_in[17];
  const float* v_p  = (const float*)d_in[18];

  char* ws = (char*)d_ws;
  bf16_t* xb   = (bf16_t*)ws; ws += (long)8 * 4096 * 256 * 2;
  bf16_t* WkT  = (bf16_t*)ws; ws += (long)128 * 256 * 2;
  bf16_t* WvT  = (bf16_t*)ws; ws += (long)512 * 256 * 2;
  bf16_t* Wq_t = (bf16_t*)ws; ws += (long)128 * 256 * 2;
  bf16_t* Wp_t = (bf16_t*)ws; ws += (long)512 * 512 * 2;
  bf16_t* Qbuf = (bf16_t*)ws; ws += (long)64 * 1024 * 32 * 2;
  bf16_t* Kbuf = (bf16_t*)ws; ws += (long)64 * 4096 * 16 * 2;
  bf16_t* Vtb  = (bf16_t*)ws; ws += (long)64 * 64 * 4096 * 2;
  bf16_t* outp = (bf16_t*)ws; ws += (long)8192 * 512 * 2;

  cvt_f32_bf16<<<dim3(4096), 256, 0, stream>>>(x, xb, (long)8 * 4096 * 256);

  wkv_split_transpose<<<dim3(20, 8), dim3(32, 8), 0, stream>>>(Wkv, WkT, WvT);
  transpose_f32_bf16<<<dim3(4, 8),   dim3(32, 8), 0, stream>>>(Wq, Wq_t, 256, 128);
  transpose_f32_bf16<<<dim3(16, 16), dim3(32, 8), 0, stream>>>(Wp, Wp_t, 512, 512);

  gemm_bn<0><<<dim3(512, 2), 256, 0, stream>>>(xb, WkT, bkv, g_kv, b_kv, m_kv, v_kv, Kbuf, nullptr);
  gemm_bn<3><<<dim3(8, 512), 256, 0, stream>>>(WvT, xb, bkv, g_kv, b_kv, m_kv, v_kv, Vtb, nullptr);
  gemm_bn<1><<<dim3(128, 2), 256, 0, stream>>>(xb, Wq_t, bq, g_q, b_q, m_q, v_q, Qbuf, nullptr);

  attn_kernel<<<dim3(1024), 512, 0, stream>>>(Qbuf, Kbuf, Vtb, outp);

  gemm_bn<2><<<dim3(128, 8), 256, 0, stream>>>(outp, Wp_t, bp, g_p, b_p, m_p, v_p, nullptr, (float*)d_out);
}

// Round 7
// 414.051 us; speedup vs baseline: 1.1669x; 1.1669x over previous
//
#include <hip/hip_runtime.h>

typedef __bf16 bf16_t;
typedef __bf16 bf16x2 __attribute__((ext_vector_type(2)));
typedef __bf16 bf16x8 __attribute__((ext_vector_type(8)));
typedef float f32x4 __attribute__((ext_vector_type(4)));

#define BN_EPS 1e-3f

// ---------------- fp32 -> bf16 elementwise convert (8 elems/thread) ----------------
__global__ __launch_bounds__(256) void cvt_f32_bf16(
    const float* __restrict__ in, bf16_t* __restrict__ out, long n)
{
  long i = ((long)blockIdx.x * 256 + threadIdx.x) * 8;
  if (i + 8 > n) return;
  f32x4 a = *(const f32x4*)(in + i);
  f32x4 b = *(const f32x4*)(in + i + 4);
  bf16x8 o;
  o[0] = (bf16_t)a[0]; o[1] = (bf16_t)a[1]; o[2] = (bf16_t)a[2]; o[3] = (bf16_t)a[3];
  o[4] = (bf16_t)b[0]; o[5] = (bf16_t)b[1]; o[6] = (bf16_t)b[2]; o[7] = (bf16_t)b[3];
  *(bf16x8*)(out + i) = o;
}

// ---------------- weight transpose fp32 in[R][C] -> bf16 out[C][R] ----------------
__global__ __launch_bounds__(256) void transpose_f32_bf16(
    const float* __restrict__ in, bf16_t* __restrict__ out, int R, int C)
{
  __shared__ bf16_t t[32][33];
  int bx = blockIdx.x * 32, by = blockIdx.y * 32;
  int tx = threadIdx.x, ty = threadIdx.y;
#pragma unroll
  for (int i = 0; i < 32; i += 8)
    t[ty + i][tx] = (bf16_t)in[(long)(by + ty + i) * C + (bx + tx)];
  __syncthreads();
#pragma unroll
  for (int i = 0; i < 32; i += 8)
    out[(long)(bx + ty + i) * R + (by + tx)] = t[tx][ty + i];
}

// ------- Wkv split-transpose: fp32 [256][640] -> WkT[128][256], WvT[512][256] bf16 -------
__global__ __launch_bounds__(256) void wkv_split_transpose(
    const float* __restrict__ in, bf16_t* __restrict__ outK, bf16_t* __restrict__ outV)
{
  __shared__ bf16_t t[32][33];
  int bx = blockIdx.x * 32, by = blockIdx.y * 32;   // bx over 640 cols, by over 256 rows
  int tx = threadIdx.x, ty = threadIdx.y;
#pragma unroll
  for (int i = 0; i < 32; i += 8)
    t[ty + i][tx] = (bf16_t)in[(long)(by + ty + i) * 640 + (bx + tx)];
  __syncthreads();
#pragma unroll
  for (int i = 0; i < 32; i += 8) {
    int c = bx + ty + i;                 // kv channel 0..639
    int h = c / 80, r80 = c - h * 80;
    bf16_t v = t[tx][ty + i];
    if (r80 < 16)
      outK[(long)(h * 16 + r80) * 256 + (by + tx)] = v;
    else
      outV[(long)(h * 64 + (r80 - 16)) * 256 + (by + tx)] = v;
  }
}

// ---------------- fused GEMM + BN (+ scatter epilogues) ----------------
// MODE 0: K   A=xb[32768][256], WkT[128][256] -> K[bh][4096][16]
// MODE 1: Q   A=xb (strided row gather), WqT[128][256] -> Q[bh][1024][32] (pad 0, *0.25*log2e)
// MODE 2: PROJ A=outp[8192][512], WpT[512][512] -> d_out fp32 [8192][512]
// MODE 3: V^T A=WvT[512][256], B=xb -> Vt[bh*64+dv][4096]  (coalesced Vt writes)
template <int MODE>
__global__ __launch_bounds__(256) void gemm_bn(
    const bf16_t* __restrict__ A, const bf16_t* __restrict__ Wt,
    const float* __restrict__ bias, const float* __restrict__ gamma,
    const float* __restrict__ beta, const float* __restrict__ mean,
    const float* __restrict__ var,
    bf16_t* __restrict__ out0, float* __restrict__ outf)
{
  constexpr int KTOT = (MODE == 2) ? 512 : 256;
  const int lane = threadIdx.x & 63;
  const int w = threadIdx.x >> 6;
  const int quad = lane >> 4, l15 = lane & 15;
  const int m0 = blockIdx.x * 64 + w * 16;
  const int n0 = blockIdx.y * 64;

  int mrow = m0 + l15;
  int arow;
  if constexpr (MODE == 1) {
    int b = mrow >> 10, qp = mrow & 1023;
    arow = (b << 12) + ((qp >> 5) << 7) + ((qp & 31) << 1);
  } else {
    arow = mrow;
  }
  const bf16_t* ap = A + (long)arow * KTOT + quad * 8;
  const bf16_t* bp = Wt + (long)(n0 + l15) * KTOT + quad * 8;

  f32x4 acc[4] = {};
#pragma unroll
  for (int ks = 0; ks < KTOT / 32; ks++) {
    bf16x8 a = *(const bf16x8*)(ap + ks * 32);
#pragma unroll
    for (int nt = 0; nt < 4; nt++) {
      bf16x8 bfr = *(const bf16x8*)(bp + (long)nt * 16 * KTOT + ks * 32);
      acc[nt] = __builtin_amdgcn_mfma_f32_16x16x32_bf16(a, bfr, acc[nt], 0, 0, 0);
    }
  }

  if constexpr (MODE == 3) {
    // rows = V channels, cols = x rows. BN per ROW.
    float sB[4], tB[4], bB[4];
#pragma unroll
    for (int r = 0; r < 4; r++) {
      int ch = m0 + quad * 4 + r;                      // 0..511
      int c = (ch >> 6) * 80 + 16 + (ch & 63);         // kv param index
      sB[r] = gamma[c] / sqrtf(var[c] + BN_EPS);
      tB[r] = beta[c] - mean[c] * sB[r];
      bB[r] = bias[c];
    }
#pragma unroll
    for (int nt = 0; nt < 4; nt++) {
      int n = n0 + nt * 16 + l15;                      // x row
      int b = n >> 12, seq = n & 4095;
#pragma unroll
      for (int r = 0; r < 4; r++) {
        int ch = m0 + quad * 4 + r;
        float y = (acc[nt][r] + bB[r]) * sB[r] + tB[r];
        out0[((long)((b * 8 + (ch >> 6)) * 64 + (ch & 63))) * 4096 + seq] = (bf16_t)y;
      }
    }
    return;
  }

#pragma unroll
  for (int nt = 0; nt < 4; nt++) {
    int col = n0 + nt * 16 + l15;
    int cp;
    if constexpr (MODE == 0) cp = (col >> 4) * 80 + (col & 15);
    else cp = col;
    float s = gamma[cp] / sqrtf(var[cp] + BN_EPS);
    float t = beta[cp] - mean[cp] * s;
    float bia = bias[cp];
#pragma unroll
    for (int r = 0; r < 4; r++) {
      int grow = m0 + quad * 4 + r;
      float y = (acc[nt][r] + bia) * s + t;
      if constexpr (MODE == 0) {
        int h = col >> 4, d = col & 15;
        int b = grow >> 12, seq = grow & 4095;
        out0[((long)((b * 8 + h) * 4096 + seq)) * 16 + d] = (bf16_t)y;   // K [bh][seq][16]
      } else if constexpr (MODE == 1) {
        int h = col >> 4, d = col & 15;
        int b = grow >> 10, qp = grow & 1023;
        long qi = ((long)((b * 8 + h) * 1024 + qp)) * 32 + d;
        out0[qi] = (bf16_t)(y * 0.36067376f);  // 0.25 (kd^-.5) * log2(e), for exp2 softmax
        out0[qi + 16] = (bf16_t)0.f;           // zero-pad d 16..31 (K-overread harmless)
      } else {
        outf[(long)grow * 512 + col] = y;
      }
    }
  }
}

// ---------------- flash attention: 4 waves = 4-way key split, 32 q rows/block ----------------
// grid 2048: bh = blockIdx&63 (XCD locality: all 32 q-blocks of a bh on one XCD),
// qb = blockIdx>>6 (32 q-blocks of 32 rows). wave w = key quarter (keys w*1024..+1024).
// Interleaved keys: kf0 = even (2*l15), kf1 = odd -> P writes pack to b32; P stays
// natural key order so V loads / P reads unchanged. exp2 softmax (scale folded into Q).
// 256-thr block + bounds (256,3): VGPR cap ~170 >> live set -> NO SPILL (R6 lesson).
__global__ __launch_bounds__(256, 3) void attn_kernel(
    const bf16_t* __restrict__ Q, const bf16_t* __restrict__ K,
    const bf16_t* __restrict__ Vt, bf16_t* __restrict__ outp)
{
  const int tid = threadIdx.x;
  const int lane = tid & 63, w = tid >> 6;       // w = key quarter 0..3
  const int quad = lane >> 4, l15 = lane & 15;
  const int bh = blockIdx.x & 63, qb = blockIdx.x >> 6;
  const int b = bh >> 3, h = bh & 7;
  const bf16_t* Qp = Q + (long)bh * 1024 * 32;
  const bf16_t* Kp = K + (long)bh * 4096 * 16;
  const bf16_t* Vp = Vt + (long)bh * 64 * 4096;

  // P: 4 waves x 2 strips x [16 rows x stride 40] bf16 = 10240 B (head of smem)
  // combine: 3 partials x 64 lanes x 40 f32 = 30720 B (aliased after loop)
  __shared__ __align__(16) char smem[30720];
  bf16_t* Pw0 = (bf16_t*)smem + (w * 2 + 0) * 640;
  bf16_t* Pw1 = (bf16_t*)smem + (w * 2 + 1) * 640;

  const int q0 = qb * 32;
  bf16x8 qf[2];
  qf[0] = *(const bf16x8*)(Qp + (long)(q0 + l15) * 32 + quad * 8);
  qf[1] = *(const bf16x8*)(Qp + (long)(q0 + 16 + l15) * 32 + quad * 8);

  f32x4 O[2][4] = {};
  float lp[2][4] = {};
  const f32x4 zf = {0.f, 0.f, 0.f, 0.f};

  const int kstart = w * 1024;
  // kf0: key rows 2*l15 (even); kf1: 2*l15+1 (odd). Quads 2,3 overread into the
  // next K row -> multiplied by Q's zero-pad -> exact 0.
  const bf16_t* kpb = Kp + (long)(kstart + 2 * l15) * 16 + quad * 8;
  const bf16_t* vpb = Vp + (long)l15 * 4096 + kstart + quad * 8;

  auto loadK = [&](int t, bf16x8& k0, bf16x8& k1) {
    k0 = *(const bf16x8*)(kpb + (long)t * 512);
    k1 = *(const bf16x8*)(kpb + (long)t * 512 + 16);
  };
  auto loadV = [&](int t, bf16x8* v) {
#pragma unroll
    for (int dt = 0; dt < 4; dt++)
      v[dt] = *(const bf16x8*)(vpb + (long)dt * 65536 + t * 32);
  };
  auto qk_part = [&](bf16x8 kf0, bf16x8 kf1) {
#pragma unroll
    for (int s = 0; s < 2; s++) {
      f32x4 S0 = __builtin_amdgcn_mfma_f32_16x16x32_bf16(qf[s], kf0, zf, 0, 0, 0);
      f32x4 S1 = __builtin_amdgcn_mfma_f32_16x16x32_bf16(qf[s], kf1, zf, 0, 0, 0);
      bf16_t* P = s ? Pw1 : Pw0;
#pragma unroll
      for (int r = 0; r < 4; r++) {
        float p0 = exp2f(S0[r]);       // key 2*l15 (+tile)
        float p1 = exp2f(S1[r]);       // key 2*l15+1
        lp[s][r] += p0 + p1;
        bf16x2 pk; pk[0] = (bf16_t)p0; pk[1] = (bf16_t)p1;
        *(bf16x2*)(P + (quad * 4 + r) * 40 + 2 * l15) = pk;   // packed b32 write
      }
    }
  };
  auto pv_part = [&](const bf16x8* vf) {
    __asm__ volatile("s_waitcnt lgkmcnt(0)" ::: "memory");
#pragma unroll
    for (int s = 0; s < 2; s++) {
      bf16x8 pf = *(const bf16x8*)((s ? Pw1 : Pw0) + l15 * 40 + quad * 8);
#pragma unroll
      for (int dt = 0; dt < 4; dt++)
        O[s][dt] = __builtin_amdgcn_mfma_f32_16x16x32_bf16(pf, vf[dt], O[s][dt], 0, 0, 0);
    }
  };

  // 2-deep copy-free pipeline over 32 tiles of 32 keys.
  // Tail loads (t=32,33) overread into adjacent workspace buffers (in-bounds, unused).
  bf16x8 ak0, ak1, bk0, bk1, av[4], bv[4];
  loadK(0, ak0, ak1); loadV(0, av);
  loadK(1, bk0, bk1); loadV(1, bv);
  for (int kt = 0; kt < 32; kt += 2) {
    qk_part(ak0, ak1);
    loadK(kt + 2, ak0, ak1);
    pv_part(av);
    loadV(kt + 2, av);
    qk_part(bk0, bk1);
    loadK(kt + 3, bk0, bk1);
    pv_part(bv);
    loadV(kt + 3, bv);
  }

  // ------- combine 4 key-quarters -------
  __syncthreads();
  float* comb = (float*)smem;
  if (w != 0) {
    float* dst = comb + ((long)(w - 1) * 64 + lane) * 40;
#pragma unroll
    for (int s = 0; s < 2; s++)
#pragma unroll
      for (int dt = 0; dt < 4; dt++)
        *(f32x4*)(dst + (s * 4 + dt) * 4) = O[s][dt];
#pragma unroll
    for (int s = 0; s < 2; s++)
#pragma unroll
      for (int r = 0; r < 4; r++)
        dst[32 + s * 4 + r] = lp[s][r];
  }
  __syncthreads();
  if (w == 0) {
#pragma unroll
    for (int j = 0; j < 3; j++) {
      const float* src = comb + ((long)j * 64 + lane) * 40;
#pragma unroll
      for (int s = 0; s < 2; s++)
#pragma unroll
        for (int dt = 0; dt < 4; dt++)
          O[s][dt] += *(const f32x4*)(src + (s * 4 + dt) * 4);
#pragma unroll
      for (int s = 0; s < 2; s++)
#pragma unroll
        for (int r = 0; r < 4; r++)
          lp[s][r] += src[32 + s * 4 + r];
    }

#pragma unroll
    for (int s = 0; s < 2; s++) {
      float lt[4];
#pragma unroll
      for (int r = 0; r < 4; r++) {
        float v = lp[s][r];
        v += __shfl_xor(v, 1);
        v += __shfl_xor(v, 2);
        v += __shfl_xor(v, 4);
        v += __shfl_xor(v, 8);
        lt[r] = v;
      }
#pragma unroll
      for (int dt = 0; dt < 4; dt++) {
        int dv = dt * 16 + l15;
#pragma unroll
        for (int r = 0; r < 4; r++) {
          int q = q0 + s * 16 + quad * 4 + r;
          float val = O[s][dt][r] / lt[r];
          float hs = val * fminf(fmaxf(val + 3.f, 0.f), 6.f) * (1.f / 6.f);
          long row = (long)h * 128 + dv * 2 + (q >> 9);
          outp[((long)b * 1024 + row) * 512 + (q & 511)] = (bf16_t)hs;
        }
      }
    }
  }
}

extern "C" void kernel_launch(void* const* d_in, const int* in_sizes, int n_in,
                              void* d_out, int out_size, void* d_ws, size_t ws_size,
                              hipStream_t stream)
{
  const float* x    = (const float*)d_in[0];
  const float* Wkv  = (const float*)d_in[1];
  const float* bkv  = (const float*)d_in[2];
  const float* g_kv = (const float*)d_in[3];
  const float* b_kv = (const float*)d_in[4];
  const float* m_kv = (const float*)d_in[5];
  const float* v_kv = (const float*)d_in[6];
  const float* Wq   = (const float*)d_in[7];
  const float* bq   = (const float*)d_in[8];
  const float* g_q  = (const float*)d_in[9];
  const float* b_q  = (const float*)d_in[10];
  const float* m_q  = (const float*)d_in[11];
  const float* v_q  = (const float*)d_in[12];
  const float* Wp   = (const float*)d_in[13];
  const float* bp   = (const float*)d_in[14];
  const float* g_p  = (const float*)d_in[15];
  const float* b_p  = (const float*)d_in[16];
  const float* m_p  = (const float*)d_in[17];
  const float* v_p  = (const float*)d_in[18];

  char* ws = (char*)d_ws;
  bf16_t* xb   = (bf16_t*)ws; ws += (long)8 * 4096 * 256 * 2;
  bf16_t* WkT  = (bf16_t*)ws; ws += (long)128 * 256 * 2;
  bf16_t* WvT  = (bf16_t*)ws; ws += (long)512 * 256 * 2;
  bf16_t* Wq_t = (bf16_t*)ws; ws += (long)128 * 256 * 2;
  bf16_t* Wp_t = (bf16_t*)ws; ws += (long)512 * 512 * 2;
  bf16_t* Qbuf = (bf16_t*)ws; ws += (long)64 * 1024 * 32 * 2;
  bf16_t* Kbuf = (bf16_t*)ws; ws += (long)64 * 4096 * 16 * 2;
  bf16_t* Vtb  = (bf16_t*)ws; ws += (long)64 * 64 * 4096 * 2;
  bf16_t* outp = (bf16_t*)ws; ws += (long)8192 * 512 * 2;

  cvt_f32_bf16<<<dim3(4096), 256, 0, stream>>>(x, xb, (long)8 * 4096 * 256);

  wkv_split_transpose<<<dim3(20, 8), dim3(32, 8), 0, stream>>>(Wkv, WkT, WvT);
  transpose_f32_bf16<<<dim3(4, 8),   dim3(32, 8), 0, stream>>>(Wq, Wq_t, 256, 128);
  transpose_f32_bf16<<<dim3(16, 16), dim3(32, 8), 0, stream>>>(Wp, Wp_t, 512, 512);

  gemm_bn<0><<<dim3(512, 2), 256, 0, stream>>>(xb, WkT, bkv, g_kv, b_kv, m_kv, v_kv, Kbuf, nullptr);
  gemm_bn<3><<<dim3(8, 512), 256, 0, stream>>>(WvT, xb, bkv, g_kv, b_kv, m_kv, v_kv, Vtb, nullptr);
  gemm_bn<1><<<dim3(128, 2), 256, 0, stream>>>(xb, Wq_t, bq, g_q, b_q, m_q, v_q, Qbuf, nullptr);

  attn_kernel<<<dim3(2048), 256, 0, stream>>>(Qbuf, Kbuf, Vtb, outp);

  gemm_bn<2><<<dim3(128, 8), 256, 0, stream>>>(outp, Wp_t, bp, g_p, b_p, m_p, v_p, nullptr, (float*)d_out);
}